// Round 9
// baseline (192.287 us; speedup 1.0000x reference)
//
#include <hip/hip_runtime.h>
#include <hip/hip_bf16.h>

#define B_ 4
#define T_ 1024
#define C_ 512
#define H_ 8

typedef __attribute__((ext_vector_type(8))) short short8;
typedef __attribute__((ext_vector_type(4))) float floatx4;

__device__ __forceinline__ unsigned short f2bs(float f) {
    __hip_bfloat16 h = __float2bfloat16(f);
    return *(unsigned short*)&h;
}
__device__ __forceinline__ float bs2f(unsigned short u) {
    __hip_bfloat16 h;
    *(unsigned short*)&h = u;
    return __bfloat162float(h);
}

__device__ __forceinline__ void gload_lds16(const void* g, void* l) {
    __builtin_amdgcn_global_load_lds(
        (const __attribute__((address_space(1))) unsigned int*)g,
        (__attribute__((address_space(3))) unsigned int*)l, 16, 0, 0);
}

// ---------------------------------------------------------------------------
// prep: Wq/Wk/Wv/Wo fp32 [k][n] -> bf16 transposed WT [n][k].
// ---------------------------------------------------------------------------
__global__ __launch_bounds__(256) void prep(
    const float* __restrict__ Wq, const float* __restrict__ Wk,
    const float* __restrict__ Wv, const float* __restrict__ Wo,
    unsigned short* __restrict__ WT)
{
    __shared__ unsigned short tileT[32][33];
    const int r = blockIdx.x, tid = threadIdx.x;
    const int w = r >> 8, tile = r & 255;
    const int k0 = (tile >> 4) * 32, n0 = (tile & 15) * 32;
    const float* W = (w == 0) ? Wq : (w == 1) ? Wk : (w == 2) ? Wv : Wo;
    unsigned short* out = WT + (size_t)w * 512 * 512;
    const int kk = tid >> 3, ns = (tid & 7) * 4;
    const float4 v = *(const float4*)&W[(size_t)(k0 + kk) * 512 + n0 + ns];
    tileT[ns + 0][kk] = f2bs(v.x);
    tileT[ns + 1][kk] = f2bs(v.y);
    tileT[ns + 2][kk] = f2bs(v.z);
    tileT[ns + 3][kk] = f2bs(v.w);
    __syncthreads();
    const int nn = tid >> 3, ks = (tid & 7) * 4;
    ushort4 o;
    o.x = tileT[nn][ks + 0]; o.y = tileT[nn][ks + 1];
    o.z = tileT[nn][ks + 2]; o.w = tileT[nn][ks + 3];
    *(ushort4*)&out[(size_t)(n0 + nn) * 512 + k0 + ks] = o;
}

// ---------------------------------------------------------------------------
// QKV projection GEMM, 128x128 tiles (R9: halves redundant fp32 A fetch+cvt
// vs 128x64).  Fused fp32->bf16 A staging, B via DMA, double-buffered.
// ---------------------------------------------------------------------------
__global__ __launch_bounds__(256) void qkv_mfma(
    const float* __restrict__ x, const float* __restrict__ cc,
    const unsigned short* __restrict__ WT,
    const float* __restrict__ bq, const float* __restrict__ bk,
    const float* __restrict__ bv,
    unsigned short* __restrict__ Qc, unsigned short* __restrict__ Kc,
    unsigned short* __restrict__ Vtg)
{
    const int z = blockIdx.z;
    const float* A32 = (z == 0) ? x : cc;
    const unsigned short* Bt = WT + (size_t)z * 262144;
    const float* bias = (z == 0) ? bq : (z == 1) ? bk : bv;
    const float scale = (z == 0) ? 0.125f : 1.0f;

    __shared__ __align__(16) unsigned short sA[2 * 128 * 32];
    __shared__ __align__(16) unsigned short sB[2 * 128 * 32];

    const int tid = threadIdx.x;
    const int wave = tid >> 6, lane = tid & 63;
    const int m0 = blockIdx.y * 128, n0 = blockIdx.x * 128;
    const int mrow = lane & 15, quad = lane >> 4, kgrp = quad * 8;
    const int mhalf = (wave & 1) * 64, noff = (wave >> 1) * 64;
    const int lrow = lane >> 2, lseg = (lane & 3) * 16;

    const int fr0 = tid >> 3;            // A-load row (0..31), 4 passes of 32
    const int fc4 = (tid & 7) * 4;       // A-load col within 32-k chunk

    floatx4 acc[4][4];
    #pragma unroll
    for (int i = 0; i < 4; i++)
        #pragma unroll
        for (int j = 0; j < 4; j++)
            acc[i][j] = (floatx4){0.f, 0.f, 0.f, 0.f};

    float4 a4[4];
    #pragma unroll
    for (int p = 0; p < 4; p++)
        a4[p] = *(const float4*)&A32[(size_t)(m0 + fr0 + p * 32) * 512 + fc4];
    #pragma unroll
    for (int j = 0; j < 2; j++) {
        const int rB = wave * 32 + j * 16 + lrow;
        gload_lds16((const char*)Bt + ((size_t)(n0 + rB) * 512) * 2 + lseg,
                    &sB[(size_t)(wave * 32 + j * 16) * 32]);
    }
    #pragma unroll
    for (int p = 0; p < 4; p++) {
        ushort4 o;
        o.x = f2bs(a4[p].x); o.y = f2bs(a4[p].y);
        o.z = f2bs(a4[p].z); o.w = f2bs(a4[p].w);
        *(ushort4*)&sA[(fr0 + p * 32) * 32 + fc4] = o;
    }

    for (int ck = 0; ck < 16; ck++) {
        const int buf = ck & 1;
        __syncthreads();
        if (ck < 15) {
            const int k0 = (ck + 1) * 32;
            #pragma unroll
            for (int j = 0; j < 2; j++) {
                const int rB = wave * 32 + j * 16 + lrow;
                gload_lds16((const char*)Bt + ((size_t)(n0 + rB) * 512 + k0) * 2 + lseg,
                            &sB[(size_t)((buf ^ 1) * 128 + wave * 32 + j * 16) * 32]);
            }
            #pragma unroll
            for (int p = 0; p < 4; p++)
                a4[p] = *(const float4*)&A32[(size_t)(m0 + fr0 + p * 32) * 512 + k0 + fc4];
        }
        const unsigned short* sAb = sA + (size_t)buf * 128 * 32;
        const unsigned short* sBb = sB + (size_t)buf * 128 * 32;
        short8 af[4], bfv[4];
        #pragma unroll
        for (int i = 0; i < 4; i++)
            af[i] = *(const short8*)&sAb[(size_t)(mhalf + i * 16 + mrow) * 32 + kgrp];
        #pragma unroll
        for (int i = 0; i < 4; i++)
            bfv[i] = *(const short8*)&sBb[(size_t)(noff + i * 16 + mrow) * 32 + kgrp];
        #pragma unroll
        for (int mt = 0; mt < 4; mt++)
            #pragma unroll
            for (int nt = 0; nt < 4; nt++)
                acc[mt][nt] = __builtin_amdgcn_mfma_f32_16x16x32_bf16(
                    af[mt], bfv[nt], acc[mt][nt], 0, 0, 0);
        if (ck < 15) {
            unsigned short* dst = sA + (size_t)(buf ^ 1) * 128 * 32;
            #pragma unroll
            for (int p = 0; p < 4; p++) {
                ushort4 o;
                o.x = f2bs(a4[p].x); o.y = f2bs(a4[p].y);
                o.z = f2bs(a4[p].z); o.w = f2bs(a4[p].w);
                *(ushort4*)&dst[(fr0 + p * 32) * 32 + fc4] = o;
            }
        }
    }

    const int rowq = quad * 4;
    if (z < 2) {
        unsigned short* Y = (z == 0) ? Qc : Kc;
        #pragma unroll
        for (int nt = 0; nt < 4; nt++) {
            const int n = n0 + noff + nt * 16 + mrow;
            const float bv_ = bias[n];
            const int h = n >> 6, d = n & 63;
            #pragma unroll
            for (int mt = 0; mt < 4; mt++)
                #pragma unroll
                for (int r = 0; r < 4; r++) {
                    const int m = m0 + mhalf + mt * 16 + rowq + r;
                    const int bb = m >> 10, t = m & 1023;
                    Y[(((size_t)bb * H_ + h) * 1024 + t) * 64 + d] =
                        f2bs((acc[mt][nt][r] + bv_) * scale);
                }
        }
    } else {
        #pragma unroll
        for (int nt = 0; nt < 4; nt++) {
            const int n = n0 + noff + nt * 16 + mrow;
            const float bv_ = bias[n];
            const int h = n >> 6, d = n & 63;
            #pragma unroll
            for (int mt = 0; mt < 4; mt++) {
                const int m = m0 + mhalf + mt * 16 + rowq;
                const int bb = m >> 10, t = m & 1023;
                ushort4 o4;
                o4.x = f2bs(acc[mt][nt][0] + bv_);
                o4.y = f2bs(acc[mt][nt][1] + bv_);
                o4.z = f2bs(acc[mt][nt][2] + bv_);
                o4.w = f2bs(acc[mt][nt][3] + bv_);
                *(ushort4*)&Vtg[(((size_t)bb * H_ + h) * 64 + d) * 1024 + t] = o4;
            }
        }
    }
}

// ---------------------------------------------------------------------------
// Output projection GEMM, 128x64 tiles, bf16 A via DMA, double-buffered.
// ---------------------------------------------------------------------------
__global__ __launch_bounds__(256) void out_mfma(
    const unsigned short* __restrict__ AOb, const unsigned short* __restrict__ WoT,
    const float* __restrict__ bias, float* __restrict__ out)
{
    __shared__ __align__(16) unsigned short sA[2 * 128 * 32];
    __shared__ __align__(16) unsigned short sB[2 * 64 * 32];

    const int tid = threadIdx.x;
    const int wave = tid >> 6, lane = tid & 63;
    const int m0 = blockIdx.y * 128, n0 = blockIdx.x * 64;
    const int mrow = lane & 15, quad = lane >> 4, kgrp = quad * 8;
    const int mhalf = (wave & 1) * 64, noff = (wave >> 1) * 32;
    const int lrow = lane >> 2, lseg = (lane & 3) * 16;

    floatx4 acc[4][2];
    #pragma unroll
    for (int i = 0; i < 4; i++)
        #pragma unroll
        for (int j = 0; j < 2; j++)
            acc[i][j] = (floatx4){0.f, 0.f, 0.f, 0.f};

    auto stage = [&](int k0, int bufi) {
        #pragma unroll
        for (int j = 0; j < 2; j++) {
            const int rA = wave * 32 + j * 16 + lrow;
            gload_lds16((const char*)AOb + ((size_t)(m0 + rA) * 512 + k0) * 2 + lseg,
                        &sA[(size_t)(bufi * 128 + wave * 32 + j * 16) * 32]);
        }
        const int rB = wave * 16 + lrow;
        gload_lds16((const char*)WoT + ((size_t)(n0 + rB) * 512 + k0) * 2 + lseg,
                    &sB[(size_t)(bufi * 64 + wave * 16) * 32]);
    };

    stage(0, 0);
    for (int ck = 0; ck < 16; ck++) {
        const int buf = ck & 1;
        __syncthreads();
        if (ck < 15) stage((ck + 1) * 32, buf ^ 1);
        const unsigned short* sAb = sA + (size_t)buf * 128 * 32;
        const unsigned short* sBb = sB + (size_t)buf * 64 * 32;
        short8 af[4], bfv[2];
        #pragma unroll
        for (int i = 0; i < 4; i++)
            af[i] = *(const short8*)&sAb[(size_t)(mhalf + i * 16 + mrow) * 32 + kgrp];
        #pragma unroll
        for (int i = 0; i < 2; i++)
            bfv[i] = *(const short8*)&sBb[(size_t)(noff + i * 16 + mrow) * 32 + kgrp];
        #pragma unroll
        for (int mt = 0; mt < 4; mt++)
            #pragma unroll
            for (int nt = 0; nt < 2; nt++)
                acc[mt][nt] = __builtin_amdgcn_mfma_f32_16x16x32_bf16(
                    af[mt], bfv[nt], acc[mt][nt], 0, 0, 0);
    }

    const int rowq = quad * 4;
    #pragma unroll
    for (int nt = 0; nt < 2; nt++) {
        const int n = n0 + noff + nt * 16 + mrow;
        const float bv_ = bias[n];
        #pragma unroll
        for (int mt = 0; mt < 4; mt++)
            #pragma unroll
            for (int r = 0; r < 4; r++) {
                const int m = m0 + mhalf + mt * 16 + rowq + r;
                out[(size_t)m * 512 + n] = acc[mt][nt][r] + bv_;
            }
    }
}

// ---------------------------------------------------------------------------
// R9 attention: s-split ACROSS WAVES, zero in-loop barriers.
// Block = 64 t-rows of one bh; wave w owns s in [256w, 256w+256) and computes
// partial O/l for ALL 64 t.  K/V fragments loaded directly global->VGPR
// (wave-unique, L2-resident: 256 KB per bh).  P round-trips through
// wave-private LDS (A-layout).  Cross-wave merge via LDS ds_add_f32 atomics,
// one barrier, then normalize + band rel-v + store.
// Fixed-max softmax (scores bounded; validated R8, absmax 2.4e-3).
// ---------------------------------------------------------------------------
__global__ __launch_bounds__(256, 2) void attn_mfma(
    const unsigned short* __restrict__ Qc, const unsigned short* __restrict__ Kc,
    const unsigned short* __restrict__ Vtg,
    const float* __restrict__ rk, const float* __restrict__ rv,
    unsigned short* __restrict__ AOb)
{
    __shared__ float qbL[64 * 9];                      // q . rel_k  [t][w]
    __shared__ float bandL[64 * 9];                    // raw band p [t][w]
    __shared__ float rvL[9 * 64];
    __shared__ float lL[64];
    __shared__ __align__(16) float ObufL[64 * 68];     // [t][d pad68] merge buf
    __shared__ __align__(16) unsigned short PL[4][64 * 72];  // per-wave P [t][s]

    const int tb = blockIdx.x, bh = blockIdx.y;
    const int b = bh >> 3, h = bh & 7;
    const int tid = threadIdx.x;
    const int wave = tid >> 6, lane = tid & 63;
    const int t0 = tb * 64;
    const size_t qkbase = (size_t)bh * T_ * 64;
    const size_t vtbase = (size_t)bh * 64 * T_;
    const int mrow = lane & 15, quad = lane >> 4, kgrp = quad * 8;

    // ---- prologue: zero merge buffers, stage rv, qb dots
    for (int i = tid; i < 64 * 68; i += 256) ObufL[i] = 0.f;
    if (tid < 64) lL[tid] = 0.f;
    for (int idx = tid; idx < 576; idx += 256) {
        bandL[idx] = 0.f;
        rvL[idx] = rv[idx];
        const int row = idx / 9, w = idx - row * 9;
        const unsigned short* qp = &Qc[qkbase + (size_t)(t0 + row) * 64];
        float s0a = 0.f, s1a = 0.f, s2a = 0.f, s3a = 0.f;
        #pragma unroll
        for (int d8 = 0; d8 < 8; d8 += 4) {
            const short8 q0 = *(const short8*)&qp[d8 * 8];
            const short8 q1 = *(const short8*)&qp[(d8 + 1) * 8];
            const short8 q2 = *(const short8*)&qp[(d8 + 2) * 8];
            const short8 q3 = *(const short8*)&qp[(d8 + 3) * 8];
            #pragma unroll
            for (int i = 0; i < 8; i++) {
                s0a = fmaf(bs2f((unsigned short)q0[i]), rk[w * 64 + d8 * 8 + i], s0a);
                s1a = fmaf(bs2f((unsigned short)q1[i]), rk[w * 64 + (d8 + 1) * 8 + i], s1a);
                s2a = fmaf(bs2f((unsigned short)q2[i]), rk[w * 64 + (d8 + 2) * 8 + i], s2a);
                s3a = fmaf(bs2f((unsigned short)q3[i]), rk[w * 64 + (d8 + 3) * 8 + i], s3a);
            }
        }
        qbL[idx] = (s0a + s1a) + (s2a + s3a);
    }

    // Q B-frags for the block's 4 t-tiles (held in registers all kernel)
    short8 bQ0[4], bQ1[4];
    #pragma unroll
    for (int tt = 0; tt < 4; tt++) {
        const unsigned short* qp = &Qc[qkbase + (size_t)(t0 + tt * 16 + mrow) * 64];
        bQ0[tt] = *(const short8*)&qp[kgrp];
        bQ1[tt] = *(const short8*)&qp[32 + kgrp];
    }

    floatx4 Oc[4][4];                                  // [tt][dt]
    float lacc[4] = {0.f, 0.f, 0.f, 0.f};              // per tt, t = tt*16+mrow
    #pragma unroll
    for (int i = 0; i < 4; i++)
        #pragma unroll
        for (int j = 0; j < 4; j++)
            Oc[i][j] = (floatx4){0.f, 0.f, 0.f, 0.f};

    unsigned short* Pw = &PL[wave][0];

    __syncthreads();                                   // init + qb visible

    const int sw0 = wave * 256;
    for (int ck = 0; ck < 4; ck++) {
        const int s0 = sw0 + ck * 64;

        // K A-frags (m<->s) and V B-frags (n<->d) direct from global (L2)
        short8 aK0[4], aK1[4];
        #pragma unroll
        for (int st = 0; st < 4; st++) {
            const unsigned short* kp = &Kc[qkbase + (size_t)(s0 + st * 16 + mrow) * 64];
            aK0[st] = *(const short8*)&kp[kgrp];
            aK1[st] = *(const short8*)&kp[32 + kgrp];
        }
        short8 bV[2][4];
        #pragma unroll
        for (int c = 0; c < 2; c++)
            #pragma unroll
            for (int dt = 0; dt < 4; dt++)
                bV[c][dt] = *(const short8*)&Vtg[vtbase + (size_t)(dt * 16 + mrow) * 1024
                                                 + s0 + c * 32 + kgrp];

        // S^T = K Q^T: C row<->s (quad*4+r), col<->t (mrow)
        floatx4 Sc[4][4];
        #pragma unroll
        for (int st = 0; st < 4; st++)
            #pragma unroll
            for (int tt = 0; tt < 4; tt++) {
                floatx4 s4 = {0.f, 0.f, 0.f, 0.f};
                s4 = __builtin_amdgcn_mfma_f32_16x16x32_bf16(aK0[st], bQ0[tt], s4, 0, 0, 0);
                s4 = __builtin_amdgcn_mfma_f32_16x16x32_bf16(aK1[st], bQ1[tt], s4, 0, 0, 0);
                Sc[st][tt] = s4;
            }

        // fixed-max softmax; band bias/capture on the <=3 straddling tiles
        #pragma unroll
        for (int st = 0; st < 4; st++) {
            #pragma unroll
            for (int tt = 0; tt < 4; tt++) {
                const int diff0 = (s0 + st * 16) - (t0 + tt * 16);
                const int tl = tt * 16 + mrow;
                if (diff0 >= -19 && diff0 <= 19) {
                    #pragma unroll
                    for (int r = 0; r < 4; r++) {
                        const int rel = diff0 + quad * 4 + r - mrow;
                        float sc = Sc[st][tt][r];
                        const bool inband = (rel >= -4) && (rel <= 4);
                        if (inband) sc += qbL[tl * 9 + rel + 4];
                        const float p = __expf(sc);
                        if (inband) bandL[tl * 9 + rel + 4] = p;
                        Sc[st][tt][r] = p;
                    }
                } else {
                    #pragma unroll
                    for (int r = 0; r < 4; r++)
                        Sc[st][tt][r] = __expf(Sc[st][tt][r]);
                }
                lacc[tt] += (Sc[st][tt][0] + Sc[st][tt][1])
                          + (Sc[st][tt][2] + Sc[st][tt][3]);
                ushort4 o4;
                o4.x = f2bs(Sc[st][tt][0]); o4.y = f2bs(Sc[st][tt][1]);
                o4.z = f2bs(Sc[st][tt][2]); o4.w = f2bs(Sc[st][tt][3]);
                *(ushort4*)&Pw[tl * 72 + st * 16 + quad * 4] = o4;
            }
        }

        // O += P V: A = P[t][s] from wave-private LDS, B = V frags in regs
        #pragma unroll
        for (int c = 0; c < 2; c++)
            #pragma unroll
            for (int tt = 0; tt < 4; tt++) {
                const short8 aP = *(const short8*)&Pw[(tt * 16 + mrow) * 72 + c * 32 + kgrp];
                #pragma unroll
                for (int dt = 0; dt < 4; dt++)
                    Oc[tt][dt] = __builtin_amdgcn_mfma_f32_16x16x32_bf16(
                        aP, bV[c][dt], Oc[tt][dt], 0, 0, 0);
            }
    }

    // ---- merge: l (quad-reduce then atomic), O via ds_add_f32
    #pragma unroll
    for (int tt = 0; tt < 4; tt++) {
        float lv = lacc[tt];
        lv += __shfl_xor(lv, 16);
        lv += __shfl_xor(lv, 32);
        if (quad == 0) atomicAdd(&lL[tt * 16 + mrow], lv);
    }
    #pragma unroll
    for (int tt = 0; tt < 4; tt++)
        #pragma unroll
        for (int dt = 0; dt < 4; dt++)
            #pragma unroll
            for (int r = 0; r < 4; r++)
                atomicAdd(&ObufL[(tt * 16 + quad * 4 + r) * 68 + dt * 16 + mrow],
                          Oc[tt][dt][r]);
    __syncthreads();

    // ---- finalize: wave w handles t-rows [16w,16w+16), lane = d
    for (int i = 0; i < 16; i++) {
        const int tl = wave * 16 + i;
        const float inv = 1.f / lL[tl];
        float o = ObufL[tl * 68 + lane];
        #pragma unroll
        for (int w = 0; w < 9; w++)
            o = fmaf(bandL[tl * 9 + w], rvL[w * 64 + lane], o);
        AOb[((size_t)b * 1024 + t0 + tl) * 512 + h * 64 + lane] = f2bs(o * inv);
    }
}

// ---------------------------------------------------------------------------
extern "C" void kernel_launch(void* const* d_in, const int* in_sizes, int n_in,
                              void* d_out, int out_size, void* d_ws, size_t ws_size,
                              hipStream_t stream)
{
    const float* x  = (const float*)d_in[0];
    const float* c  = (const float*)d_in[1];
    const float* Wq = (const float*)d_in[2];
    const float* bq = (const float*)d_in[3];
    const float* Wk = (const float*)d_in[4];
    const float* bk = (const float*)d_in[5];
    const float* Wv = (const float*)d_in[6];
    const float* bv = (const float*)d_in[7];
    const float* Wo = (const float*)d_in[8];
    const float* bo = (const float*)d_in[9];
    const float* rk = (const float*)d_in[10];
    const float* rv = (const float*)d_in[11];

    unsigned short* WT  = (unsigned short*)d_ws;           // 4x [512n][512k] bf16
    unsigned short* Qc  = WT + (size_t)4 * 512 * 512;      // [32][1024][64] bf16
    unsigned short* Kc  = Qc + (size_t)32 * 1024 * 64;
    unsigned short* Vtg = Kc + (size_t)32 * 1024 * 64;     // [32][64][1024] bf16
    unsigned short* AOb = Vtg + (size_t)32 * 1024 * 64;    // [4096][512] bf16

    prep<<<1024, 256, 0, stream>>>(Wq, Wk, Wv, Wo, WT);
    qkv_mfma<<<dim3(4, 32, 3), 256, 0, stream>>>(x, c, WT, bq, bk, bv, Qc, Kc, Vtg);
    attn_mfma<<<dim3(16, 32), 256, 0, stream>>>(Qc, Kc, Vtg, rk, rv, AOb);
    out_mfma<<<dim3(8, 32), 256, 0, stream>>>(AOb, WT + (size_t)3 * 262144, bo, (float*)d_out);
}

// Round 10
// 151.511 us; speedup vs baseline: 1.2691x; 1.2691x over previous
//
#include <hip/hip_runtime.h>
#include <hip/hip_bf16.h>

#define B_ 4
#define T_ 1024
#define C_ 512
#define H_ 8

typedef __attribute__((ext_vector_type(8))) short short8;
typedef __attribute__((ext_vector_type(4))) float floatx4;

__device__ __forceinline__ unsigned short f2bs(float f) {
    __hip_bfloat16 h = __float2bfloat16(f);
    return *(unsigned short*)&h;
}
__device__ __forceinline__ float bs2f(unsigned short u) {
    __hip_bfloat16 h;
    *(unsigned short*)&h = u;
    return __bfloat162float(h);
}

__device__ __forceinline__ void gload_lds16(const void* g, void* l) {
    __builtin_amdgcn_global_load_lds(
        (const __attribute__((address_space(1))) unsigned int*)g,
        (__attribute__((address_space(3))) unsigned int*)l, 16, 0, 0);
}

// ---------------------------------------------------------------------------
// prep: Wq/Wk/Wv/Wo fp32 [k][n] -> bf16 transposed WT [n][k].
// ---------------------------------------------------------------------------
__global__ __launch_bounds__(256) void prep(
    const float* __restrict__ Wq, const float* __restrict__ Wk,
    const float* __restrict__ Wv, const float* __restrict__ Wo,
    unsigned short* __restrict__ WT)
{
    __shared__ unsigned short tileT[32][33];
    const int r = blockIdx.x, tid = threadIdx.x;
    const int w = r >> 8, tile = r & 255;
    const int k0 = (tile >> 4) * 32, n0 = (tile & 15) * 32;
    const float* W = (w == 0) ? Wq : (w == 1) ? Wk : (w == 2) ? Wv : Wo;
    unsigned short* out = WT + (size_t)w * 512 * 512;
    const int kk = tid >> 3, ns = (tid & 7) * 4;
    const float4 v = *(const float4*)&W[(size_t)(k0 + kk) * 512 + n0 + ns];
    tileT[ns + 0][kk] = f2bs(v.x);
    tileT[ns + 1][kk] = f2bs(v.y);
    tileT[ns + 2][kk] = f2bs(v.z);
    tileT[ns + 3][kk] = f2bs(v.w);
    __syncthreads();
    const int nn = tid >> 3, ks = (tid & 7) * 4;
    ushort4 o;
    o.x = tileT[nn][ks + 0]; o.y = tileT[nn][ks + 1];
    o.z = tileT[nn][ks + 2]; o.w = tileT[nn][ks + 3];
    *(ushort4*)&out[(size_t)(n0 + nn) * 512 + k0 + ks] = o;
}

// ---------------------------------------------------------------------------
// QKV projection GEMM, 128x128 tiles.  Fused fp32->bf16 A staging, B via DMA,
// double-buffered.  Q,K -> [bh][t][64]; V -> [bh][d][t].
// ---------------------------------------------------------------------------
__global__ __launch_bounds__(256) void qkv_mfma(
    const float* __restrict__ x, const float* __restrict__ cc,
    const unsigned short* __restrict__ WT,
    const float* __restrict__ bq, const float* __restrict__ bk,
    const float* __restrict__ bv,
    unsigned short* __restrict__ Qc, unsigned short* __restrict__ Kc,
    unsigned short* __restrict__ Vtg)
{
    const int z = blockIdx.z;
    const float* A32 = (z == 0) ? x : cc;
    const unsigned short* Bt = WT + (size_t)z * 262144;
    const float* bias = (z == 0) ? bq : (z == 1) ? bk : bv;
    const float scale = (z == 0) ? 0.125f : 1.0f;

    __shared__ __align__(16) unsigned short sA[2 * 128 * 32];
    __shared__ __align__(16) unsigned short sB[2 * 128 * 32];

    const int tid = threadIdx.x;
    const int wave = tid >> 6, lane = tid & 63;
    const int m0 = blockIdx.y * 128, n0 = blockIdx.x * 128;
    const int mrow = lane & 15, quad = lane >> 4, kgrp = quad * 8;
    const int mhalf = (wave & 1) * 64, noff = (wave >> 1) * 64;
    const int lrow = lane >> 2, lseg = (lane & 3) * 16;

    const int fr0 = tid >> 3;            // A-load row (0..31), 4 passes of 32
    const int fc4 = (tid & 7) * 4;       // A-load col within 32-k chunk

    floatx4 acc[4][4];
    #pragma unroll
    for (int i = 0; i < 4; i++)
        #pragma unroll
        for (int j = 0; j < 4; j++)
            acc[i][j] = (floatx4){0.f, 0.f, 0.f, 0.f};

    float4 a4[4];
    #pragma unroll
    for (int p = 0; p < 4; p++)
        a4[p] = *(const float4*)&A32[(size_t)(m0 + fr0 + p * 32) * 512 + fc4];
    #pragma unroll
    for (int j = 0; j < 2; j++) {
        const int rB = wave * 32 + j * 16 + lrow;
        gload_lds16((const char*)Bt + ((size_t)(n0 + rB) * 512) * 2 + lseg,
                    &sB[(size_t)(wave * 32 + j * 16) * 32]);
    }
    #pragma unroll
    for (int p = 0; p < 4; p++) {
        ushort4 o;
        o.x = f2bs(a4[p].x); o.y = f2bs(a4[p].y);
        o.z = f2bs(a4[p].z); o.w = f2bs(a4[p].w);
        *(ushort4*)&sA[(fr0 + p * 32) * 32 + fc4] = o;
    }

    for (int ck = 0; ck < 16; ck++) {
        const int buf = ck & 1;
        __syncthreads();
        if (ck < 15) {
            const int k0 = (ck + 1) * 32;
            #pragma unroll
            for (int j = 0; j < 2; j++) {
                const int rB = wave * 32 + j * 16 + lrow;
                gload_lds16((const char*)Bt + ((size_t)(n0 + rB) * 512 + k0) * 2 + lseg,
                            &sB[(size_t)((buf ^ 1) * 128 + wave * 32 + j * 16) * 32]);
            }
            #pragma unroll
            for (int p = 0; p < 4; p++)
                a4[p] = *(const float4*)&A32[(size_t)(m0 + fr0 + p * 32) * 512 + k0 + fc4];
        }
        const unsigned short* sAb = sA + (size_t)buf * 128 * 32;
        const unsigned short* sBb = sB + (size_t)buf * 128 * 32;
        short8 af[4], bfv[4];
        #pragma unroll
        for (int i = 0; i < 4; i++)
            af[i] = *(const short8*)&sAb[(size_t)(mhalf + i * 16 + mrow) * 32 + kgrp];
        #pragma unroll
        for (int i = 0; i < 4; i++)
            bfv[i] = *(const short8*)&sBb[(size_t)(noff + i * 16 + mrow) * 32 + kgrp];
        #pragma unroll
        for (int mt = 0; mt < 4; mt++)
            #pragma unroll
            for (int nt = 0; nt < 4; nt++)
                acc[mt][nt] = __builtin_amdgcn_mfma_f32_16x16x32_bf16(
                    af[mt], bfv[nt], acc[mt][nt], 0, 0, 0);
        if (ck < 15) {
            unsigned short* dst = sA + (size_t)(buf ^ 1) * 128 * 32;
            #pragma unroll
            for (int p = 0; p < 4; p++) {
                ushort4 o;
                o.x = f2bs(a4[p].x); o.y = f2bs(a4[p].y);
                o.z = f2bs(a4[p].z); o.w = f2bs(a4[p].w);
                *(ushort4*)&dst[(fr0 + p * 32) * 32 + fc4] = o;
            }
        }
    }

    const int rowq = quad * 4;
    if (z < 2) {
        unsigned short* Y = (z == 0) ? Qc : Kc;
        #pragma unroll
        for (int nt = 0; nt < 4; nt++) {
            const int n = n0 + noff + nt * 16 + mrow;
            const float bv_ = bias[n];
            const int h = n >> 6, d = n & 63;
            #pragma unroll
            for (int mt = 0; mt < 4; mt++)
                #pragma unroll
                for (int r = 0; r < 4; r++) {
                    const int m = m0 + mhalf + mt * 16 + rowq + r;
                    const int bb = m >> 10, t = m & 1023;
                    Y[(((size_t)bb * H_ + h) * 1024 + t) * 64 + d] =
                        f2bs((acc[mt][nt][r] + bv_) * scale);
                }
        }
    } else {
        #pragma unroll
        for (int nt = 0; nt < 4; nt++) {
            const int n = n0 + noff + nt * 16 + mrow;
            const float bv_ = bias[n];
            const int h = n >> 6, d = n & 63;
            #pragma unroll
            for (int mt = 0; mt < 4; mt++) {
                const int m = m0 + mhalf + mt * 16 + rowq;
                const int bb = m >> 10, t = m & 1023;
                ushort4 o4;
                o4.x = f2bs(acc[mt][nt][0] + bv_);
                o4.y = f2bs(acc[mt][nt][1] + bv_);
                o4.z = f2bs(acc[mt][nt][2] + bv_);
                o4.w = f2bs(acc[mt][nt][3] + bv_);
                *(ushort4*)&Vtg[(((size_t)bb * H_ + h) * 64 + d) * 1024 + t] = o4;
            }
        }
    }
}

// ---------------------------------------------------------------------------
// Output projection GEMM, 128x64 tiles, bf16 A via DMA, double-buffered.
// ---------------------------------------------------------------------------
__global__ __launch_bounds__(256) void out_mfma(
    const unsigned short* __restrict__ AOb, const unsigned short* __restrict__ WoT,
    const float* __restrict__ bias, float* __restrict__ out)
{
    __shared__ __align__(16) unsigned short sA[2 * 128 * 32];
    __shared__ __align__(16) unsigned short sB[2 * 64 * 32];

    const int tid = threadIdx.x;
    const int wave = tid >> 6, lane = tid & 63;
    const int m0 = blockIdx.y * 128, n0 = blockIdx.x * 64;
    const int mrow = lane & 15, quad = lane >> 4, kgrp = quad * 8;
    const int mhalf = (wave & 1) * 64, noff = (wave >> 1) * 32;
    const int lrow = lane >> 2, lseg = (lane & 3) * 16;

    floatx4 acc[4][2];
    #pragma unroll
    for (int i = 0; i < 4; i++)
        #pragma unroll
        for (int j = 0; j < 2; j++)
            acc[i][j] = (floatx4){0.f, 0.f, 0.f, 0.f};

    auto stage = [&](int k0, int bufi) {
        #pragma unroll
        for (int j = 0; j < 2; j++) {
            const int rA = wave * 32 + j * 16 + lrow;
            gload_lds16((const char*)AOb + ((size_t)(m0 + rA) * 512 + k0) * 2 + lseg,
                        &sA[(size_t)(bufi * 128 + wave * 32 + j * 16) * 32]);
        }
        const int rB = wave * 16 + lrow;
        gload_lds16((const char*)WoT + ((size_t)(n0 + rB) * 512 + k0) * 2 + lseg,
                    &sB[(size_t)(bufi * 64 + wave * 16) * 32]);
    };

    stage(0, 0);
    for (int ck = 0; ck < 16; ck++) {
        const int buf = ck & 1;
        __syncthreads();
        if (ck < 15) stage((ck + 1) * 32, buf ^ 1);
        const unsigned short* sAb = sA + (size_t)buf * 128 * 32;
        const unsigned short* sBb = sB + (size_t)buf * 64 * 32;
        short8 af[4], bfv[2];
        #pragma unroll
        for (int i = 0; i < 4; i++)
            af[i] = *(const short8*)&sAb[(size_t)(mhalf + i * 16 + mrow) * 32 + kgrp];
        #pragma unroll
        for (int i = 0; i < 2; i++)
            bfv[i] = *(const short8*)&sBb[(size_t)(noff + i * 16 + mrow) * 32 + kgrp];
        #pragma unroll
        for (int mt = 0; mt < 4; mt++)
            #pragma unroll
            for (int nt = 0; nt < 2; nt++)
                acc[mt][nt] = __builtin_amdgcn_mfma_f32_16x16x32_bf16(
                    af[mt], bfv[nt], acc[mt][nt], 0, 0, 0);
    }

    const int rowq = quad * 4;
    #pragma unroll
    for (int nt = 0; nt < 2; nt++) {
        const int n = n0 + noff + nt * 16 + mrow;
        const float bv_ = bias[n];
        #pragma unroll
        for (int mt = 0; mt < 4; mt++)
            #pragma unroll
            for (int r = 0; r < 4; r++) {
                const int m = m0 + mhalf + mt * 16 + rowq + r;
                out[(size_t)m * 512 + n] = acc[mt][nt][r] + bv_;
            }
    }
}

// ---------------------------------------------------------------------------
// Attention (R8 structure, best-known): full s-range per block, 512 blocks.
// S^T trick (S^T = K Q^T), DMA double-buffered K/V, one barrier per chunk,
// P bf16 in per-wave LDS, l complete in-block, band rel-v in epilogue.
// ---------------------------------------------------------------------------
__device__ __forceinline__ void attn_stage(
    const unsigned short* __restrict__ Kc, const unsigned short* __restrict__ Vtg,
    size_t qkbase, size_t vtbase, int s0, int wave, int ldrow, int gseg,
    unsigned short* KLb, unsigned short* VtLb)
{
    #pragma unroll
    for (int j = 0; j < 2; j++) {
        const int br = wave * 16 + j * 8;
        gload_lds16((const char*)Kc + (qkbase + (size_t)(s0 + br + ldrow) * 64) * 2 + gseg * 16,
                    &KLb[br * 64]);
        gload_lds16((const char*)Vtg + (vtbase + (size_t)(br + ldrow) * 1024 + s0) * 2 + gseg * 16,
                    &VtLb[br * 64]);
    }
}

__global__ __launch_bounds__(256) void attn_mfma(
    const unsigned short* __restrict__ Qc, const unsigned short* __restrict__ Kc,
    const unsigned short* __restrict__ Vtg,
    const float* __restrict__ rk, const float* __restrict__ rv,
    unsigned short* __restrict__ AOb)
{
    __shared__ __align__(16) unsigned short KL[2][64 * 64];
    __shared__ __align__(16) unsigned short VtL[2][64 * 64];
    __shared__ __align__(16) unsigned short PL[4][16 * 72];
    __shared__ float qbL[64 * 9];
    __shared__ float bandL[64 * 9];
    __shared__ float rvL[9 * 64];
    __shared__ float lL[64];

    const int tb = blockIdx.x, bh = blockIdx.y;
    const int b = bh >> 3, h = bh & 7;
    const int tid = threadIdx.x;
    const int wave = tid >> 6, lane = tid & 63;
    const int t0 = tb * 64;
    const int t0w = t0 + wave * 16;
    const size_t qkbase = (size_t)bh * T_ * 64;
    const size_t vtbase = (size_t)bh * 64 * T_;

    const int mrow = lane & 15;
    const int quad = lane >> 4;
    const int kgrp = quad * 8;
    const int x7 = mrow & 7;
    const int ldrow = lane >> 3;
    const int gseg = (lane & 7) ^ ldrow;

    attn_stage(Kc, Vtg, qkbase, vtbase, 0, wave, ldrow, gseg, &KL[0][0], &VtL[0][0]);

    for (int idx = tid; idx < 576; idx += 256) {
        bandL[idx] = 0.f;
        rvL[idx] = rv[idx];
        const int row = idx / 9, w = idx - row * 9;
        const unsigned short* qp = &Qc[qkbase + (size_t)(t0 + row) * 64];
        float s0a = 0.f, s1a = 0.f, s2a = 0.f, s3a = 0.f;
        #pragma unroll
        for (int d8 = 0; d8 < 8; d8 += 4) {
            const short8 q0 = *(const short8*)&qp[d8 * 8];
            const short8 q1 = *(const short8*)&qp[(d8 + 1) * 8];
            const short8 q2 = *(const short8*)&qp[(d8 + 2) * 8];
            const short8 q3 = *(const short8*)&qp[(d8 + 3) * 8];
            #pragma unroll
            for (int i = 0; i < 8; i++) {
                s0a = fmaf(bs2f((unsigned short)q0[i]), rk[w * 64 + d8 * 8 + i], s0a);
                s1a = fmaf(bs2f((unsigned short)q1[i]), rk[w * 64 + (d8 + 1) * 8 + i], s1a);
                s2a = fmaf(bs2f((unsigned short)q2[i]), rk[w * 64 + (d8 + 2) * 8 + i], s2a);
                s3a = fmaf(bs2f((unsigned short)q3[i]), rk[w * 64 + (d8 + 3) * 8 + i], s3a);
            }
        }
        qbL[idx] = (s0a + s1a) + (s2a + s3a);
    }

    const short8 aQ0 = *(const short8*)&Qc[qkbase + (size_t)(t0w + mrow) * 64 + kgrp];
    const short8 aQ1 = *(const short8*)&Qc[qkbase + (size_t)(t0w + mrow) * 64 + 32 + kgrp];

    floatx4 Oc[4];
    float lsA[4] = {0.f, 0.f, 0.f, 0.f};
    #pragma unroll
    for (int dt = 0; dt < 4; dt++) Oc[dt] = (floatx4){0.f, 0.f, 0.f, 0.f};

    unsigned short* Pw = &PL[wave][0];
    float* qbw = &qbL[wave * 16 * 9];
    float* bandw = &bandL[wave * 16 * 9];

    for (int ck = 0; ck < 16; ck++) {
        const int s0 = ck * 64;
        const int buf = ck & 1;
        __syncthreads();
        if (ck < 15)
            attn_stage(Kc, Vtg, qkbase, vtbase, s0 + 64, wave, ldrow, gseg,
                       &KL[buf ^ 1][0], &VtL[buf ^ 1][0]);

        floatx4 Sc[4];
        #pragma unroll
        for (int st = 0; st < 4; st++) {
            const int row = st * 16 + mrow;
            const short8 aK0 = *(const short8*)&KL[buf][row * 64 + (quad ^ x7) * 8];
            const short8 aK1 = *(const short8*)&KL[buf][row * 64 + ((4 + quad) ^ x7) * 8];
            floatx4 s4 = {0.f, 0.f, 0.f, 0.f};
            s4 = __builtin_amdgcn_mfma_f32_16x16x32_bf16(aK0, aQ0, s4, 0, 0, 0);
            s4 = __builtin_amdgcn_mfma_f32_16x16x32_bf16(aK1, aQ1, s4, 0, 0, 0);
            Sc[st] = s4;
        }

        #pragma unroll
        for (int st = 0; st < 4; st++) {
            const int diff = s0 + st * 16 - t0w;
            float p0, p1, p2, p3;
            if (diff >= -19 && diff <= 19) {
                #pragma unroll
                for (int r = 0; r < 4; r++) {
                    const int rel = diff + quad * 4 + r - mrow;
                    float sc = Sc[st][r];
                    const bool inband = (rel >= -4) && (rel <= 4);
                    if (inband) sc += qbw[mrow * 9 + rel + 4];
                    const float p = __expf(sc);
                    if (inband) bandw[mrow * 9 + rel + 4] = p;
                    Sc[st][r] = p;
                }
            } else {
                #pragma unroll
                for (int r = 0; r < 4; r++) Sc[st][r] = __expf(Sc[st][r]);
            }
            p0 = Sc[st][0]; p1 = Sc[st][1]; p2 = Sc[st][2]; p3 = Sc[st][3];
            lsA[st] += (p0 + p1) + (p2 + p3);
            ushort4 o4;
            o4.x = f2bs(p0); o4.y = f2bs(p1); o4.z = f2bs(p2); o4.w = f2bs(p3);
            *(ushort4*)&Pw[mrow * 72 + st * 16 + quad * 4] = o4;
        }

        #pragma unroll
        for (int c = 0; c < 2; c++) {
            const short8 aP = *(const short8*)&Pw[mrow * 72 + c * 32 + kgrp];
            #pragma unroll
            for (int dt = 0; dt < 4; dt++) {
                const int segl = (c * 4 + quad) ^ x7;
                const short8 bV = *(const short8*)&VtL[buf][(dt * 16 + mrow) * 64 + segl * 8];
                Oc[dt] = __builtin_amdgcn_mfma_f32_16x16x32_bf16(aP, bV, Oc[dt], 0, 0, 0);
            }
        }
    }

    float lv = (lsA[0] + lsA[1]) + (lsA[2] + lsA[3]);
    lv += __shfl_xor(lv, 16);
    lv += __shfl_xor(lv, 32);
    if (quad == 0) lL[wave * 16 + mrow] = lv;

    #pragma unroll
    for (int r = 0; r < 4; r++) {
        const int tl = quad * 4 + r;
        const float inv = 1.f / lL[wave * 16 + tl];
        #pragma unroll
        for (int w = 0; w < 9; w++) {
            const float p = bandw[tl * 9 + w];
            #pragma unroll
            for (int dt = 0; dt < 4; dt++)
                Oc[dt][r] = fmaf(p, rvL[w * 64 + dt * 16 + mrow], Oc[dt][r]);
        }
        const int t = t0w + tl;
        #pragma unroll
        for (int dt = 0; dt < 4; dt++)
            AOb[((size_t)b * 1024 + t) * 512 + h * 64 + dt * 16 + mrow] =
                f2bs(Oc[dt][r] * inv);
    }
}

// ---------------------------------------------------------------------------
extern "C" void kernel_launch(void* const* d_in, const int* in_sizes, int n_in,
                              void* d_out, int out_size, void* d_ws, size_t ws_size,
                              hipStream_t stream)
{
    const float* x  = (const float*)d_in[0];
    const float* c  = (const float*)d_in[1];
    const float* Wq = (const float*)d_in[2];
    const float* bq = (const float*)d_in[3];
    const float* Wk = (const float*)d_in[4];
    const float* bk = (const float*)d_in[5];
    const float* Wv = (const float*)d_in[6];
    const float* bv = (const float*)d_in[7];
    const float* Wo = (const float*)d_in[8];
    const float* bo = (const float*)d_in[9];
    const float* rk = (const float*)d_in[10];
    const float* rv = (const float*)d_in[11];

    unsigned short* WT  = (unsigned short*)d_ws;           // 4x [512n][512k] bf16
    unsigned short* Qc  = WT + (size_t)4 * 512 * 512;      // [32][1024][64] bf16
    unsigned short* Kc  = Qc + (size_t)32 * 1024 * 64;
    unsigned short* Vtg = Kc + (size_t)32 * 1024 * 64;     // [32][64][1024] bf16
    unsigned short* AOb = Vtg + (size_t)32 * 1024 * 64;    // [4096][512] bf16

    prep<<<1024, 256, 0, stream>>>(Wq, Wk, Wv, Wo, WT);
    qkv_mfma<<<dim3(4, 32, 3), 256, 0, stream>>>(x, c, WT, bq, bk, bv, Qc, Kc, Vtg);
    attn_mfma<<<dim3(16, 32), 256, 0, stream>>>(Qc, Kc, Vtg, rk, rv, AOb);
    out_mfma<<<dim3(8, 32), 256, 0, stream>>>(AOb, WT + (size_t)3 * 262144, bo, (float*)d_out);
}